// Round 6
// baseline (406.019 us; speedup 1.0000x reference)
//
#include <hip/hip_runtime.h>

#define BHX   32      // B*H
#define NSEQ  8192
#define NMASK 8191
#define DIM   64
#define NPROJ 7
#define NBUCK 128
#define NBLK  32      // key blocks of 256
#define QBS   256
#define SSIZE 256
#define LOG32 3.4657359027997265f
#define KPAD  72      // P-buffer padded leading dim (bf16 units)

typedef unsigned short u16;
typedef unsigned int   u32;
typedef unsigned char  u8;
typedef __attribute__((ext_vector_type(8))) short bf16x8;
typedef __attribute__((ext_vector_type(4))) float f32x4;

union B8U { u32 u[4]; bf16x8 v; };

__device__ __forceinline__ u16 f2bf(float f){
    u32 u = __float_as_uint(f);
    u32 r = u + 0x7fffu + ((u >> 16) & 1u);   // RNE
    return (u16)(r >> 16);
}
__device__ __forceinline__ u32 pk2(float a, float b){
    return (u32)f2bf(a) | ((u32)f2bf(b) << 16);
}
__device__ __forceinline__ f32x4 mfma16(bf16x8 a, bf16x8 b, f32x4 c){
    return __builtin_amdgcn_mfma_f32_16x16x32_bf16(a, b, c, 0, 0, 0);
}

// Vt layout: [bh][kb][d][key] bf16
#define VTB(bh, kb, d, key) (((((size_t)(bh) * NBLK + (kb)) * DIM + (d)) * 256) + (key))

// ---------------------------------------------------------------------------
// Kernel 1a: LSH hash, LDS-tiled for coalesced HBM reads.
// grid (8 slabs, BHX, 2 tensors), 256 thr. Sequential-d fp32 accumulation
// order is IDENTICAL to the round-3..5 passing kernels (sign-exactness).
// ---------------------------------------------------------------------------
__global__ __launch_bounds__(256) void hash_kernel(
    const float* __restrict__ qg, const float* __restrict__ kg,
    const float* __restrict__ projg,
    u8* __restrict__ bkt)
{
    const int slab = blockIdx.x, bh = blockIdx.y, tz = blockIdx.z;
    const float* __restrict__ x = tz ? kg : qg;
    u8* __restrict__ ob = bkt + ((size_t)tz * BHX + bh) * NSEQ;

    __shared__ float tile[256][68];   // 68 KB, rows 272B (16B-aligned)
    __shared__ float projs[NPROJ][DIM];

    const int t = threadIdx.x;
    if (t < 112) {
        #pragma unroll
        for (int u = 0; u < 4; u++) {
            int e = t * 4 + u;
            projs[e % NPROJ][e / NPROJ] = projg[e];
        }
    }

    const size_t bhN = (size_t)bh * NSEQ;
    for (int T = 0; T < 4; T++) {
        __syncthreads();   // previous tile fully consumed
        const float* gsrc = x + (bhN + slab * 1024 + T * 256) * DIM;
        #pragma unroll
        for (int i = 0; i < 16; i++) {
            int fd  = i * 1024 + t * 4;          // dword offset within tile
            int row = fd >> 6, col = fd & 63;
            *(float4*)&tile[row][col] = *(const float4*)(gsrc + fd);
        }
        __syncthreads();

        // compute row t — exact same accumulation order as rounds 3-5
        float dot[NPROJ];
        #pragma unroll
        for (int r = 0; r < NPROJ; r++) dot[r] = 0.0f;
        #pragma unroll
        for (int c = 0; c < 16; c++) {
            float4 w = *(const float4*)&tile[t][c * 4];
            float f[4] = {w.x, w.y, w.z, w.w};
            #pragma unroll
            for (int u = 0; u < 4; u++) {
                float xv = f[u];
                int d = c * 4 + u;
                #pragma unroll
                for (int r = 0; r < NPROJ; r++) dot[r] += xv * projs[r][d];
            }
        }
        int code = 0;
        #pragma unroll
        for (int r = 0; r < NPROJ; r++) code |= (dot[r] > 0.0f ? 1 : 0) << r;
        ob[slab * 1024 + T * 256 + t] = (u8)(code ^ (code >> 1));
    }
}

// ---------------------------------------------------------------------------
// Kernel 1b: stable counting sort per (tensor, head). grid (BHX, 2), 256 thr.
// ---------------------------------------------------------------------------
__global__ __launch_bounds__(256) void sort_kernel(
    const u8* __restrict__ bkt,
    u16* __restrict__ qidx, u16* __restrict__ kidx)
{
    const int bh = blockIdx.x, tz = blockIdx.y;
    const u8* __restrict__ ib = bkt + ((size_t)tz * BHX + bh) * NSEQ;
    u16* __restrict__ idx = (tz ? kidx : qidx) + (size_t)bh * NSEQ;

    __shared__ u8  lb[NSEQ];
    __shared__ u16 hist[NBUCK][258];
    __shared__ int base[NBUCK];
    __shared__ int tot[NBUCK];

    const int t = threadIdx.x;
    {
        const uint4* src = (const uint4*)ib;
        uint4* dst = (uint4*)lb;
        dst[t] = src[t];
        dst[256 + t] = src[256 + t];
    }
    u32* hz = (u32*)&hist[0][0];
    for (int z = t; z < (NBUCK * 258) / 2; z += 256) hz[z] = 0u;
    __syncthreads();

    #pragma unroll 4
    for (int i = 0; i < 32; i++) hist[lb[t * 32 + i]][t]++;
    __syncthreads();

    if (t < NBUCK) {
        u32 run = 0;
        for (int c = 0; c < 256; c++) {
            u32 v = hist[t][c];
            hist[t][c] = (u16)run;
            run += v;
        }
        tot[t] = (int)run;
    }
    __syncthreads();
    if (t == 0) {
        int run = 0;
        for (int b = 0; b < NBUCK; b++) { base[b] = run; run += tot[b]; }
    }
    __syncthreads();

    #pragma unroll 4
    for (int i = 0; i < 32; i++) {
        int n = t * 32 + i;
        int b = lb[n];
        int pos = base[b] + hist[b][t];
        hist[b][t]++;
        idx[pos] = (u16)n;
    }
}

// ---------------------------------------------------------------------------
// Kernel 1c: gather + transpose V into bf16 [bh][kb][d][key] tiles.
// grid (NBLK, BHX), 256 thr; thread = one sorted key.
// ---------------------------------------------------------------------------
__global__ __launch_bounds__(256) void gather_v(
    const float* __restrict__ vg, const u16* __restrict__ kidx,
    u16* __restrict__ vt)
{
    const int kb = blockIdx.x, bh = blockIdx.y, t = threadIdx.x;
    const size_t bhN = (size_t)bh * NSEQ;
    const int grow = ((int)kidx[bhN + kb * 256 + t]) & NMASK;
    const float4* vr = (const float4*)(vg + (bhN + (size_t)grow) * DIM);
    float v[DIM];
    #pragma unroll
    for (int c = 0; c < 16; c++) {
        float4 w = vr[c];
        v[c * 4 + 0] = w.x; v[c * 4 + 1] = w.y;
        v[c * 4 + 2] = w.z; v[c * 4 + 3] = w.w;
    }
    #pragma unroll
    for (int d = 0; d < DIM; d++)
        vt[VTB(bh, kb, d, t)] = f2bf(v[d]);   // coalesced 128B per d across lanes
}

// ---------------------------------------------------------------------------
// Kernel 1d: sampled-key prep per bh: resolved indices, transposed SVt,
// block-id bytes for the overlap mask. grid (BHX), 256 thr.
// ---------------------------------------------------------------------------
__global__ __launch_bounds__(256) void sampled_prep(
    const float* __restrict__ vg, const u16* __restrict__ kidx,
    const int* __restrict__ samp,
    u16* __restrict__ skidx, u8* __restrict__ sblk, u16* __restrict__ svt)
{
    const int bh = blockIdx.x, t = threadIdx.x;
    const size_t bhN = (size_t)bh * NSEQ;
    const int sidx = samp[bh * SSIZE + t] & NMASK;
    const int grow = ((int)kidx[bhN + sidx]) & NMASK;
    skidx[bh * SSIZE + t] = (u16)grow;
    sblk[bh * SSIZE + t]  = (u8)(sidx >> 8);
    const float4* vr = (const float4*)(vg + (bhN + (size_t)grow) * DIM);
    float v[DIM];
    #pragma unroll
    for (int c = 0; c < 16; c++) {
        float4 w = vr[c];
        v[c * 4 + 0] = w.x; v[c * 4 + 1] = w.y;
        v[c * 4 + 2] = w.z; v[c * 4 + 3] = w.w;
    }
    #pragma unroll
    for (int d = 0; d < DIM; d++)
        svt[((size_t)bh * DIM + d) * 256 + t] = f2bf(v[d]);
}

// ---------------------------------------------------------------------------
// Kernel 2 (fast): barrier-free MFMA flash attention.
// grid (NBLK, BHX), 256 thr = 4 independent waves; wave owns 64 queries.
// K fragments: direct global gather (fp32->bf16 in-reg).
// V^T fragments: direct global bf16 from pre-transposed tiles.
// P: per-wave LDS round-trip only (36.9 KB total).
// ---------------------------------------------------------------------------
__global__ __launch_bounds__(256, 2) void attn_fast(
    const float* __restrict__ qg, const float* __restrict__ kg,
    const u16* __restrict__ vt, const u16* __restrict__ svt,
    const u16* __restrict__ qidx, const u16* __restrict__ kidx,
    const u16* __restrict__ skidx, const u8* __restrict__ sblk,
    float* __restrict__ outg)
{
    __shared__ u16 Ps[4 * 64 * KPAD];   // per-wave P buffer, 36.9 KB

    const int qb = blockIdx.x, bh = blockIdx.y, t = threadIdx.x;
    const int w = t >> 6, lane = t & 63, c = lane & 15, g = lane >> 4;
    const size_t bhN = (size_t)bh * NSEQ;

    // ---- Q fragments (gathered fp32 -> bf16, scale folded) ----
    int qi[4];
    bf16x8 qf[4][2];
    #pragma unroll
    for (int qt = 0; qt < 4; qt++) {
        qi[qt] = ((int)qidx[bhN + qb * QBS + w * 64 + qt * 16 + c]) & NMASK;
        const float* qr = qg + (bhN + (size_t)qi[qt]) * DIM;
        #pragma unroll
        for (int dk = 0; dk < 2; dk++) {
            int d0 = dk * 32 + g * 8;
            float4 x = *(const float4*)(qr + d0);
            float4 y = *(const float4*)(qr + d0 + 4);
            B8U f;
            f.u[0] = pk2(x.x * 0.125f, x.y * 0.125f);
            f.u[1] = pk2(x.z * 0.125f, x.w * 0.125f);
            f.u[2] = pk2(y.x * 0.125f, y.y * 0.125f);
            f.u[3] = pk2(y.z * 0.125f, y.w * 0.125f);
            qf[qt][dk] = f.v;
        }
    }

    f32x4 O[4][4];
    #pragma unroll
    for (int dt = 0; dt < 4; dt++)
        #pragma unroll
        for (int qt = 0; qt < 4; qt++) O[dt][qt] = (f32x4)0.0f;
    float m[4] = {-1e30f, -1e30f, -1e30f, -1e30f};
    float l[4] = {0.0f, 0.0f, 0.0f, 0.0f};

    for (int cc = 0; cc < 8; cc++) {
        const bool blk = (cc < 4);
        const u16* kri = blk ? &kidx[bhN + qb * QBS + cc * 64]
                             : &skidx[bh * SSIZE + (cc - 4) * 64];

        // ---- K fragments: gathered fp32, packed to bf16 in-register ----
        bf16x8 ka[4][2];
        #pragma unroll
        for (int kt = 0; kt < 4; kt++) {
            int r = ((int)kri[kt * 16 + c]) & NMASK;
            const float* kr = kg + (bhN + (size_t)r) * DIM;
            #pragma unroll
            for (int dk = 0; dk < 2; dk++) {
                int d0 = dk * 32 + g * 8;
                float4 x = *(const float4*)(kr + d0);
                float4 y = *(const float4*)(kr + d0 + 4);
                B8U f;
                f.u[0] = pk2(x.x, x.y);
                f.u[1] = pk2(x.z, x.w);
                f.u[2] = pk2(y.x, y.y);
                f.u[3] = pk2(y.z, y.w);
                ka[kt][dk] = f.v;
            }
        }

        // ---- additive bias rows (sampled: +log32 or -inf on overlap) ----
        f32x4 addn[4];
        if (blk) {
            #pragma unroll
            for (int kt = 0; kt < 4; kt++) addn[kt] = (f32x4)0.0f;
        } else {
            #pragma unroll
            for (int kt = 0; kt < 4; kt++) {
                u32 sb4 = *(const u32*)&sblk[bh * SSIZE + (cc - 4) * 64 + kt * 16 + g * 4];
                #pragma unroll
                for (int r = 0; r < 4; r++)
                    addn[kt][r] = (((sb4 >> (8 * r)) & 255u) == (u32)qb) ? -1e30f : LOG32;
            }
        }

        // ---- S^T per qt: MFMA, online softmax, pack P to per-wave LDS ----
        #pragma unroll
        for (int qt = 0; qt < 4; qt++) {
            f32x4 S[4];
            #pragma unroll
            for (int kt = 0; kt < 4; kt++) {
                S[kt] = (f32x4)0.0f;
                S[kt] = mfma16(ka[kt][0], qf[qt][0], S[kt]);
                S[kt] = mfma16(ka[kt][1], qf[qt][1], S[kt]);
            }
            float cmax = -1e30f;
            #pragma unroll
            for (int kt = 0; kt < 4; kt++)
                #pragma unroll
                for (int r = 0; r < 4; r++)
                    cmax = fmaxf(cmax, S[kt][r] + addn[kt][r]);
            cmax = fmaxf(cmax, __shfl_xor(cmax, 16));
            cmax = fmaxf(cmax, __shfl_xor(cmax, 32));
            float mnew  = fmaxf(m[qt], cmax);
            float alpha = __expf(m[qt] - mnew);
            m[qt] = mnew;
            float lsum = 0.0f;
            u16* prow = &Ps[(size_t)(w * 64 + qt * 16 + c) * KPAD];
            #pragma unroll
            for (int kt = 0; kt < 4; kt++) {
                float p0 = __expf(S[kt][0] + addn[kt][0] - mnew);
                float p1 = __expf(S[kt][1] + addn[kt][1] - mnew);
                float p2 = __expf(S[kt][2] + addn[kt][2] - mnew);
                float p3 = __expf(S[kt][3] + addn[kt][3] - mnew);
                lsum += (p0 + p1) + (p2 + p3);
                u32* pw = (u32*)&prow[kt * 16 + g * 4];
                pw[0] = pk2(p0, p1);
                pw[1] = pk2(p2, p3);
            }
            lsum += __shfl_xor(lsum, 16);
            lsum += __shfl_xor(lsum, 32);
            l[qt] = l[qt] * alpha + lsum;
            #pragma unroll
            for (int dt = 0; dt < 4; dt++) O[dt][qt] *= alpha;
        }

        // ---- V^T fragments direct from global bf16; PV MFMA ----
        const u16* vtb = blk ? &vt[VTB(bh, qb, 0, cc * 64)]
                             : &svt[((size_t)bh * DIM) * 256 + (cc - 4) * 64];
        #pragma unroll
        for (int kk = 0; kk < 2; kk++) {
            bf16x8 vfr[4], pfr[4];
            #pragma unroll
            for (int dt = 0; dt < 4; dt++)
                vfr[dt] = *(const bf16x8*)&vtb[(size_t)(dt * 16 + c) * 256 + kk * 32 + g * 8];
            #pragma unroll
            for (int qt = 0; qt < 4; qt++)
                pfr[qt] = *(const bf16x8*)&Ps[(size_t)(w * 64 + qt * 16 + c) * KPAD + kk * 32 + g * 8];
            #pragma unroll
            for (int dt = 0; dt < 4; dt++)
                #pragma unroll
                for (int qt = 0; qt < 4; qt++)
                    O[dt][qt] = mfma16(vfr[dt], pfr[qt], O[dt][qt]);
        }
        // no __syncthreads: Ps regions are wave-private; same-wave LDS deps
        // are ordered by lgkmcnt which the compiler inserts.
    }

    #pragma unroll
    for (int qt = 0; qt < 4; qt++) {
        float inv = 1.0f / fmaxf(l[qt], 1e-30f);
        float* orow = outg + (bhN + (size_t)qi[qt]) * DIM;
        #pragma unroll
        for (int dt = 0; dt < 4; dt++) {
            f32x4 o = O[dt][qt] * inv;
            *(f32x4*)(orow + dt * 16 + g * 4) = o;
        }
    }
}

// ---------------------------------------------------------------------------
// Fallback attention (round-5 proven, needs only 1.5 MB ws).
// ---------------------------------------------------------------------------
__global__ __launch_bounds__(256, 2) void attn_mfma(
    const float* __restrict__ qg, const float* __restrict__ kg,
    const float* __restrict__ vg,
    const u16* __restrict__ qidx, const u16* __restrict__ kidx,
    const int* __restrict__ samp,
    float* __restrict__ outg)
{
    __shared__ u16  Ks[64 * KPAD];
    __shared__ u16  Vt[64 * KPAD];
    __shared__ u16  Ps[4 * 64 * KPAD];
    __shared__ float addv[64];

    const int qb = blockIdx.x, bh = blockIdx.y, t = threadIdx.x;
    const int w = t >> 6, lane = t & 63, c = lane & 15, g = lane >> 4;
    const size_t bhN = (size_t)bh * NSEQ;

    int qi[4];
    bf16x8 qf[4][2];
    #pragma unroll
    for (int qt = 0; qt < 4; qt++) {
        qi[qt] = ((int)qidx[bhN + qb * QBS + w * 64 + qt * 16 + c]) & NMASK;
        const float* qr = qg + (bhN + (size_t)qi[qt]) * DIM;
        #pragma unroll
        for (int dk = 0; dk < 2; dk++) {
            int d0 = dk * 32 + g * 8;
            float4 x = *(const float4*)(qr + d0);
            float4 y = *(const float4*)(qr + d0 + 4);
            B8U f;
            f.u[0] = pk2(x.x * 0.125f, x.y * 0.125f);
            f.u[1] = pk2(x.z * 0.125f, x.w * 0.125f);
            f.u[2] = pk2(y.x * 0.125f, y.y * 0.125f);
            f.u[3] = pk2(y.z * 0.125f, y.w * 0.125f);
            qf[qt][dk] = f.v;
        }
    }

    f32x4 O[4][4];
    #pragma unroll
    for (int dt = 0; dt < 4; dt++)
        #pragma unroll
        for (int qt = 0; qt < 4; qt++) O[dt][qt] = (f32x4)0.0f;
    float m[4] = {-1e30f, -1e30f, -1e30f, -1e30f};
    float l[4] = {0.0f, 0.0f, 0.0f, 0.0f};

    for (int cc = 0; cc < 8; cc++) {
        __syncthreads();
        {
            int s = t >> 2, seg = (t & 3) * 16;
            int grow; float add;
            if (cc < 4) {
                grow = ((int)kidx[bhN + qb * QBS + cc * 64 + s]) & NMASK;
                add  = 0.0f;
            } else {
                int sidx = samp[bh * SSIZE + (cc - 4) * 64 + s] & NMASK;
                grow = ((int)kidx[bhN + sidx]) & NMASK;
                add  = ((sidx >> 8) == qb) ? -1e30f : LOG32;
            }
            const float4* kr = (const float4*)(kg + (bhN + (size_t)grow) * DIM + seg);
            float4 a = kr[0], b = kr[1], e = kr[2], d = kr[3];
            u32* dst = (u32*)&Ks[s * KPAD + seg];
            dst[0] = pk2(a.x, a.y); dst[1] = pk2(a.z, a.w);
            dst[2] = pk2(b.x, b.y); dst[3] = pk2(b.z, b.w);
            dst[4] = pk2(e.x, e.y); dst[5] = pk2(e.z, e.w);
            dst[6] = pk2(d.x, d.y); dst[7] = pk2(d.z, d.w);
            const float4* vr = (const float4*)(vg + (bhN + (size_t)grow) * DIM + seg);
            float4 va = vr[0], vb = vr[1], vc = vr[2], vd = vr[3];
            float vv[16] = {va.x, va.y, va.z, va.w, vb.x, vb.y, vb.z, vb.w,
                            vc.x, vc.y, vc.z, vc.w, vd.x, vd.y, vd.z, vd.w};
            #pragma unroll
            for (int i = 0; i < 16; i++) Vt[(seg + i) * KPAD + s] = f2bf(vv[i]);
            if ((t & 3) == 0) addv[s] = add;
        }
        __syncthreads();

        f32x4 addn[4];
        #pragma unroll
        for (int kt = 0; kt < 4; kt++)
            addn[kt] = *(const f32x4*)&addv[kt * 16 + g * 4];

        bf16x8 ka[4][2];
        #pragma unroll
        for (int kt = 0; kt < 4; kt++)
            #pragma unroll
            for (int dk = 0; dk < 2; dk++)
                ka[kt][dk] = *(const bf16x8*)&Ks[(kt * 16 + c) * KPAD + dk * 32 + g * 8];

        #pragma unroll
        for (int qt = 0; qt < 4; qt++) {
            f32x4 S[4];
            #pragma unroll
            for (int kt = 0; kt < 4; kt++) {
                S[kt] = (f32x4)0.0f;
                S[kt] = mfma16(ka[kt][0], qf[qt][0], S[kt]);
                S[kt] = mfma16(ka[kt][1], qf[qt][1], S[kt]);
            }
            float cmax = -1e30f;
            #pragma unroll
            for (int kt = 0; kt < 4; kt++)
                #pragma unroll
                for (int r = 0; r < 4; r++)
                    cmax = fmaxf(cmax, S[kt][r] + addn[kt][r]);
            cmax = fmaxf(cmax, __shfl_xor(cmax, 16));
            cmax = fmaxf(cmax, __shfl_xor(cmax, 32));
            float mnew  = fmaxf(m[qt], cmax);
            float alpha = __expf(m[qt] - mnew);
            m[qt] = mnew;
            float lsum = 0.0f;
            u16* prow = &Ps[(size_t)(w * 64 + qt * 16 + c) * KPAD];
            #pragma unroll
            for (int kt = 0; kt < 4; kt++) {
                float p0 = __expf(S[kt][0] + addn[kt][0] - mnew);
                float p1 = __expf(S[kt][1] + addn[kt][1] - mnew);
                float p2 = __expf(S[kt][2] + addn[kt][2] - mnew);
                float p3 = __expf(S[kt][3] + addn[kt][3] - mnew);
                lsum += (p0 + p1) + (p2 + p3);
                u32* pw = (u32*)&prow[kt * 16 + g * 4];
                pw[0] = pk2(p0, p1);
                pw[1] = pk2(p2, p3);
            }
            lsum += __shfl_xor(lsum, 16);
            lsum += __shfl_xor(lsum, 32);
            l[qt] = l[qt] * alpha + lsum;
            #pragma unroll
            for (int dt = 0; dt < 4; dt++) O[dt][qt] *= alpha;
        }

        #pragma unroll
        for (int kk = 0; kk < 2; kk++) {
            bf16x8 vfr[4], pfr[4];
            #pragma unroll
            for (int dt = 0; dt < 4; dt++)
                vfr[dt] = *(const bf16x8*)&Vt[(dt * 16 + c) * KPAD + kk * 32 + g * 8];
            #pragma unroll
            for (int qt = 0; qt < 4; qt++)
                pfr[qt] = *(const bf16x8*)&Ps[(size_t)(w * 64 + qt * 16 + c) * KPAD + kk * 32 + g * 8];
            #pragma unroll
            for (int dt = 0; dt < 4; dt++)
                #pragma unroll
                for (int qt = 0; qt < 4; qt++)
                    O[dt][qt] = mfma16(vfr[dt], pfr[qt], O[dt][qt]);
        }
    }

    #pragma unroll
    for (int qt = 0; qt < 4; qt++) {
        float inv = 1.0f / fmaxf(l[qt], 1e-30f);
        float* orow = outg + (bhN + (size_t)qi[qt]) * DIM;
        #pragma unroll
        for (int dt = 0; dt < 4; dt++) {
            f32x4 o = O[dt][qt] * inv;
            *(f32x4*)(orow + dt * 16 + g * 4) = o;
        }
    }
}

// ---------------------------------------------------------------------------
extern "C" void kernel_launch(void* const* d_in, const int* in_sizes, int n_in,
                              void* d_out, int out_size, void* d_ws, size_t ws_size,
                              hipStream_t stream)
{
    const float* qg   = (const float*)d_in[0];
    const float* kg   = (const float*)d_in[1];
    const float* vg   = (const float*)d_in[2];
    const float* pg   = (const float*)d_in[3];
    const int*   samp = (const int*)d_in[4];
    float* outg = (float*)d_out;

    char* ws = (char*)d_ws;
    size_t off = 0;
    u16* qidx  = (u16*)(ws + off); off += (size_t)BHX * NSEQ * 2;       // 512 KB
    u16* kidx  = (u16*)(ws + off); off += (size_t)BHX * NSEQ * 2;       // 512 KB
    u8*  bkt   = (u8*) (ws + off); off += (size_t)2 * BHX * NSEQ;       // 512 KB
    u16* skidx = (u16*)(ws + off); off += (size_t)BHX * SSIZE * 2;      // 16 KB
    u8*  sblk  = (u8*) (ws + off); off += (size_t)BHX * SSIZE;          // 8 KB
    off = (off + 255) & ~(size_t)255;
    u16* svt   = (u16*)(ws + off); off += (size_t)BHX * DIM * 256 * 2;  // 1 MB
    u16* vt    = (u16*)(ws + off); off += (size_t)BHX * NBLK * DIM * 256 * 2; // 32 MB
    const bool fast = (ws_size >= off);

    hipLaunchKernelGGL(hash_kernel, dim3(8, BHX, 2), dim3(256), 0, stream,
                       qg, kg, pg, bkt);
    hipLaunchKernelGGL(sort_kernel, dim3(BHX, 2), dim3(256), 0, stream,
                       bkt, qidx, kidx);
    if (fast) {
        hipLaunchKernelGGL(gather_v, dim3(NBLK, BHX), dim3(256), 0, stream,
                           vg, kidx, vt);
        hipLaunchKernelGGL(sampled_prep, dim3(BHX), dim3(256), 0, stream,
                           vg, kidx, samp, skidx, sblk, svt);
        hipLaunchKernelGGL(attn_fast, dim3(NBLK, BHX), dim3(256), 0, stream,
                           qg, kg, vt, svt, qidx, kidx, skidx, sblk, outg);
    } else {
        hipLaunchKernelGGL(attn_mfma, dim3(NBLK, BHX), dim3(256), 0, stream,
                           qg, kg, vg, qidx, kidx, samp, outg);
    }
}